// Round 5
// baseline (947.212 us; speedup 1.0000x reference)
//
#include <hip/hip_runtime.h>

#define ALPHA 0.9f
#define BETA  0.8f
#define K     25
#define B     128
#define T     16
#define IN_DIM 14400
#define NPB    16    // neurons per block-iteration (256 thr = 16 n x 16 b)
#define SLOTS  192   // block slots per batch-slice; grid = 8*SLOTS = 1536
                     // = 6 blocks/CU -> ALL resident => blockIdx%8 == XCD
                     // mapping holds exactly (the round-3/4 lesson: grids
                     // larger than residency scramble slice->XCD and
                     // re-inflate FETCH 8x).

// ---------------------------------------------------------------------------
// Transpose one 8-timestep slab of x: (B, T, IN) slab [t0,t0+8) -> xTh
// [8][IN_DIM][B]. float4 on both global sides; LDS 64x65 tile.
// ---------------------------------------------------------------------------
__global__ __launch_bounds__(256) void transpose_x4_kernel(
    const float* __restrict__ x, float* __restrict__ xTh, int t0) {
  __shared__ float tile[64][65];
  const int tl = blockIdx.z;            // local t 0..7
  const int t  = t0 + tl;
  const int i0 = blockIdx.x * 64;       // feature tile
  const int b0 = blockIdx.y * 64;       // batch tile
  const int tid = threadIdx.x;

  const int fi = (tid & 15) * 4;        // feature quad
  const int bi = tid >> 4;              // batch row 0..15
#pragma unroll
  for (int p = 0; p < 4; ++p) {
    const int b = bi + p * 16;
    const float4 v = *(const float4*)&x[(size_t)(b0 + b) * (T * IN_DIM) +
                                        (size_t)t * IN_DIM + i0 + fi];
    tile[fi + 0][b] = v.x;
    tile[fi + 1][b] = v.y;
    tile[fi + 2][b] = v.z;
    tile[fi + 3][b] = v.w;
  }
  __syncthreads();
  const int bq = (tid & 15) * 4;        // batch quad
  const int fr = tid >> 4;              // feature row 0..15
#pragma unroll
  for (int p = 0; p < 4; ++p) {
    const int f = fr + p * 16;
    float4 v;
    v.x = tile[f][bq + 0];
    v.y = tile[f][bq + 1];
    v.z = tile[f][bq + 2];
    v.w = tile[f][bq + 3];
    *(float4*)&xTh[((size_t)tl * IN_DIM + (i0 + f)) * B + b0 + bq] = v;
  }
}

// ---------------------------------------------------------------------------
// One LCN+LIF layer over nt timesteps, persistent slice-pinned blocks.
// hsrc: [nt][dprev][B], memout: [nt][dim][B]. blockIdx%8 = batch-16 slice
// (= XCD under round-robin dispatch; grid kept <= residency so it's exact).
// Each block loops neuron groups g += slots within its slice only.
// ---------------------------------------------------------------------------
__global__ __launch_bounds__(256, 6) void lcn_layer_persist(
    const float* __restrict__ hsrc, const float* __restrict__ w,
    const float* __restrict__ bias, const int* __restrict__ knn,
    float* __restrict__ memout, float* __restrict__ state,
    int dim, int dprev, int nt, int load_state, int save_state,
    int ngroups, int slots) {
  const int e  = blockIdx.x & 7;          // batch-16 slice -> XCD
  const int j0 = blockIdx.x >> 3;         // slot within slice
  const int nl = threadIdx.x >> 4;        // neuron within group (0..15)
  const int bl = threadIdx.x & 15;        // batch within slice (0..15)
  const int b  = e * 16 + bl;

  const int dB     = dim * B;
  const int dprevB = dprev * B;

  for (int g = j0; g < ngroups; g += slots) {
    const int d   = g * NPB + nl;
    const bool act = d < dim;
    const int dc  = act ? d : (dim - 1);  // clamped for loads

    int   idx[K];
    float wr[K];
#pragma unroll
    for (int k = 0; k < K; ++k) {
      idx[k] = knn[dc * K + k] * B + b;
      wr[k]  = w[dc * K + k];
    }
    const float bi = bias[dc];

    float s = 0.f, m = 0.f;
    if (load_state) {
      s = state[(size_t)dc * B + b];
      m = state[(size_t)dB + (size_t)dc * B + b];
    }

    for (int t = 0; t < nt; ++t) {
      const float* hp = hsrc + (size_t)t * dprevB;
      float h[K];
#pragma unroll
      for (int k = 0; k < K; ++k) h[k] = hp[idx[k]];
      float acc = bi;
#pragma unroll
      for (int k = 0; k < K; ++k) acc = fmaf(wr[k], h[k], acc);
      s = ALPHA * s + acc;
      const float r = (m > 1.0f) ? 1.0f : 0.0f;  // reset from PREVIOUS mem
      m = BETA * m + s - r;
      if (act) memout[(size_t)t * dB + (size_t)d * B + b] = m;
    }

    if (save_state && act) {
      state[(size_t)d * B + b]              = s;
      state[(size_t)dB + (size_t)d * B + b] = m;
    }
  }
}

// Final FC on the last timestep's layer-4 membrane. out[b][j], j in {0,1}.
__global__ __launch_bounds__(128) void fc_kernel(
    const float* __restrict__ mem4,  // [450][B]
    const float* __restrict__ fc_w,  // [2][450]
    const float* __restrict__ fc_b,  // [2]
    float* __restrict__ out) {       // [B][2]
  const int b = threadIdx.x;
  float a0 = fc_b[0], a1 = fc_b[1];
  for (int d = 0; d < 450; ++d) {
    const float h = mem4[d * B + b];
    a0 += fc_w[d] * h;
    a1 += fc_w[450 + d] * h;
  }
  out[b * 2 + 0] = a0;
  out[b * 2 + 1] = a1;
}

static inline int layer_slots(int ngroups) {
  return ngroups < SLOTS ? ngroups : SLOTS;
}

extern "C" void kernel_launch(void* const* d_in, const int* in_sizes, int n_in,
                              void* d_out, int out_size, void* d_ws,
                              size_t ws_size, hipStream_t stream) {
  (void)in_sizes; (void)n_in; (void)out_size; (void)ws_size;
  const float* x = (const float*)d_in[0];
  const float* w[5];
  const float* bias[5];
  const int* knn[5];
  for (int i = 0; i < 5; ++i) {
    w[i]    = (const float*)d_in[1 + 3 * i];
    bias[i] = (const float*)d_in[2 + 3 * i];
    knn[i]  = (const int*)d_in[3 + 3 * i];
  }
  const float* fc_w = (const float*)d_in[16];
  const float* fc_b = (const float*)d_in[17];
  float* out = (float*)d_out;

  static const int DIMS[5] = {7200, 3600, 1800, 900, 450};

  // Workspace layout (floats), 125.3 MB total:
  //   A  : 16*7200*128 = 14,745,600   (mem0 -> mem2 -> mem4)
  //   XB : 8*14400*128 = 14,745,600   (xT half-slab; later mem1 + mem3)
  //   S  : 2*7200*128  =  1,843,200   (layer-0 syn/mem carry between stages)
  float* A  = (float*)d_ws;
  float* XB = A + 14745600;
  float* S  = XB + 14745600;

  float* mem0 = A;                    // [16][7200][128]
  float* mem1 = XB;                   // [16][3600][128] (xT dead by then)
  float* mem2 = A;                    // [16][1800][128] (mem0 dead)
  float* mem3 = XB + 7372800;         // [16][900][128]
  float* mem4 = A;                    // [16][450][128]  (mem2 dead)

  // ---- Layer 0 in two 8-timestep stages (xT half-slab reuse) ----
  {
    const int ng = (DIMS[0] + NPB - 1) / NPB;  // 450
    const int sl = layer_slots(ng);            // 192
    for (int stage = 0; stage < 2; ++stage) {
      const int t0 = stage * 8;
      transpose_x4_kernel<<<dim3(IN_DIM / 64, B / 64, 8), 256, 0, stream>>>(
          x, XB, t0);
      lcn_layer_persist<<<sl * 8, 256, 0, stream>>>(
          XB, w[0], bias[0], knn[0], mem0 + (size_t)t0 * DIMS[0] * B, S,
          DIMS[0], IN_DIM, 8, /*load=*/stage, /*save=*/stage == 0, ng, sl);
    }
  }

  // ---- Layers 1..4, all 16 timesteps each ----
  const float* src = mem0;
  float* dsts[4] = {mem1, mem2, mem3, mem4};
  for (int i = 1; i < 5; ++i) {
    const int ng = (DIMS[i] + NPB - 1) / NPB;
    const int sl = layer_slots(ng);
    lcn_layer_persist<<<sl * 8, 256, 0, stream>>>(
        src, w[i], bias[i], knn[i], dsts[i - 1], nullptr, DIMS[i],
        DIMS[i - 1], 16, 0, 0, ng, sl);
    src = dsts[i - 1];
  }

  fc_kernel<<<1, 128, 0, stream>>>(mem4 + (size_t)15 * DIMS[4] * B, fc_w,
                                   fc_b, out);
}

// Round 6
// 408.058 us; speedup vs baseline: 2.3213x; 2.3213x over previous
//
#include <hip/hip_runtime.h>

#define ALPHA 0.9f
#define BETA  0.8f
#define K     25
#define B     128
#define T     16
#define IN_DIM 14400
#define NSL   8      // batch slices (= XCDs)
#define SW    16     // slice width (batch elems)
#define NPG   16     // neurons per group (256 thr = 16 n x 16 b)
#define SLOTS 192    // max slots/slice; grid <= 1536 = 6 blk/CU co-resident

// ---------------------------------------------------------------------------
// Transpose one 8-t slab of x (B,T,IN) -> xTh[8t][8e][IN][16] (slice-major:
// every 128B line belongs to exactly one XCD's slice).
// ---------------------------------------------------------------------------
__global__ __launch_bounds__(256) void transpose_x4_kernel(
    const float* __restrict__ x, float* __restrict__ xTh, int t0) {
  __shared__ float tile[64][65];
  const int tl = blockIdx.z;            // local t 0..7
  const int t  = t0 + tl;
  const int i0 = blockIdx.x * 64;       // feature tile
  const int b0 = blockIdx.y * 64;       // batch tile
  const int tid = threadIdx.x;

  const int fi = (tid & 15) * 4;        // feature quad
  const int bi = tid >> 4;              // batch row 0..15
#pragma unroll
  for (int p = 0; p < 4; ++p) {
    const int b = bi + p * 16;
    const float4 v = *(const float4*)&x[(size_t)(b0 + b) * (T * IN_DIM) +
                                        (size_t)t * IN_DIM + i0 + fi];
    tile[fi + 0][b] = v.x;
    tile[fi + 1][b] = v.y;
    tile[fi + 2][b] = v.z;
    tile[fi + 3][b] = v.w;
  }
  __syncthreads();
  const int bq = (tid & 15) * 4;        // batch quad (0,4,..,60)
  const int fr = tid >> 4;              // feature row 0..15
  const int e  = (b0 + bq) >> 4;        // slice
  const int bl = bq & 15;               // 0,4,8,12 (b0 is multiple of 64)
#pragma unroll
  for (int p = 0; p < 4; ++p) {
    const int f = fr + p * 16;
    float4 v;
    v.x = tile[f][bq + 0];
    v.y = tile[f][bq + 1];
    v.z = tile[f][bq + 2];
    v.w = tile[f][bq + 3];
    *(float4*)&xTh[(((size_t)tl * NSL + e) * IN_DIM + (i0 + f)) * SW + bl] = v;
  }
}

// ---------------------------------------------------------------------------
// LCN+LIF layer, t-OUTER persistent form. hsrc: [nt][8][dprev][16],
// memout: [nt][8][dim][16], state: [2][8][dim][16].
// blockIdx%8 = slice = XCD (grid <= 1536 co-resident => exact round-robin).
// All blocks sweep t together (t outer); per-block group states live in
// registers s[NITER]/m[NITER] with compile-time NITER (static indexing).
// ---------------------------------------------------------------------------
template <int NITER>
__global__ __launch_bounds__(256, 6) void lcn_layer_tout(
    const float* __restrict__ hsrc, const float* __restrict__ w,
    const float* __restrict__ bias, const int* __restrict__ knn,
    float* __restrict__ memout, float* __restrict__ state,
    int dim, int dprev, int nt, int load_state, int save_state,
    int ngroups, int slots) {
  const int e  = blockIdx.x & 7;          // slice -> XCD
  const int j0 = blockIdx.x >> 3;         // slot within slice
  const int nl = threadIdx.x >> 4;        // neuron within group (0..15)
  const int bl = threadIdx.x & 15;        // batch within slice (0..15)

  float s[NITER], m[NITER];
#pragma unroll
  for (int gi = 0; gi < NITER; ++gi) { s[gi] = 0.f; m[gi] = 0.f; }

  if (load_state) {
#pragma unroll
    for (int gi = 0; gi < NITER; ++gi) {
      const int g = j0 + gi * slots;
      if (g < ngroups) {
        const int d  = g * NPG + nl;
        const int dc = d < dim ? d : dim - 1;
        const size_t so = ((size_t)e * dim + dc) * SW + bl;
        s[gi] = state[so];
        m[gi] = state[(size_t)NSL * dim * SW + so];
      }
    }
  }

  for (int t = 0; t < nt; ++t) {
    const float* hp = hsrc + ((size_t)t * NSL + e) * dprev * SW;
    float* mp = memout + ((size_t)t * NSL + e) * dim * SW;
#pragma unroll
    for (int gi = 0; gi < NITER; ++gi) {
      const int g = j0 + gi * slots;
      if (g >= ngroups) continue;
      const int d    = g * NPG + nl;
      const bool act = d < dim;
      const int dc   = act ? d : dim - 1;
      const int* kp    = knn + dc * K;
      const float* wp  = w + dc * K;
      float h[K];
#pragma unroll
      for (int k = 0; k < K; ++k) h[k] = hp[kp[k] * SW + bl];
      float acc = bias[dc];
#pragma unroll
      for (int k = 0; k < K; ++k) acc = fmaf(wp[k], h[k], acc);
      s[gi] = ALPHA * s[gi] + acc;
      const float r = (m[gi] > 1.0f) ? 1.0f : 0.0f;  // reset from PREVIOUS mem
      m[gi] = BETA * m[gi] + s[gi] - r;
      if (act) mp[d * SW + bl] = m[gi];
    }
  }

  if (save_state) {
#pragma unroll
    for (int gi = 0; gi < NITER; ++gi) {
      const int g = j0 + gi * slots;
      if (g < ngroups) {
        const int d = g * NPG + nl;
        if (d < dim) {
          const size_t so = ((size_t)e * dim + d) * SW + bl;
          state[so] = s[gi];
          state[(size_t)NSL * dim * SW + so] = m[gi];
        }
      }
    }
  }
}

// Final FC on last timestep's layer-4 membrane: mem4_t15 [8][450][16].
__global__ __launch_bounds__(128) void fc_kernel(
    const float* __restrict__ mem4_t15, const float* __restrict__ fc_w,
    const float* __restrict__ fc_b, float* __restrict__ out) {
  const int b  = threadIdx.x;
  const int e  = b >> 4;
  const int bl = b & 15;
  float a0 = fc_b[0], a1 = fc_b[1];
  for (int d = 0; d < 450; ++d) {
    const float h = mem4_t15[((size_t)e * 450 + d) * SW + bl];
    a0 += fc_w[d] * h;
    a1 += fc_w[450 + d] * h;
  }
  out[b * 2 + 0] = a0;
  out[b * 2 + 1] = a1;
}

static void launch_layer(const float* src, const float* w, const float* b,
                         const int* knn, float* dst, float* st, int dim,
                         int dprev, int nt, int ld, int sv,
                         hipStream_t stream) {
  const int ng = (dim + NPG - 1) / NPG;
  const int sl = ng < SLOTS ? ng : SLOTS;
  const int ni = (ng + sl - 1) / sl;
  const dim3 grid(sl * NSL);
  if (ni == 1) {
    lcn_layer_tout<1><<<grid, 256, 0, stream>>>(src, w, b, knn, dst, st, dim,
                                                dprev, nt, ld, sv, ng, sl);
  } else if (ni == 2) {
    lcn_layer_tout<2><<<grid, 256, 0, stream>>>(src, w, b, knn, dst, st, dim,
                                                dprev, nt, ld, sv, ng, sl);
  } else {
    lcn_layer_tout<3><<<grid, 256, 0, stream>>>(src, w, b, knn, dst, st, dim,
                                                dprev, nt, ld, sv, ng, sl);
  }
}

extern "C" void kernel_launch(void* const* d_in, const int* in_sizes, int n_in,
                              void* d_out, int out_size, void* d_ws,
                              size_t ws_size, hipStream_t stream) {
  (void)in_sizes; (void)n_in; (void)out_size; (void)ws_size;
  const float* x = (const float*)d_in[0];
  const float* w[5];
  const float* bias[5];
  const int* knn[5];
  for (int i = 0; i < 5; ++i) {
    w[i]    = (const float*)d_in[1 + 3 * i];
    bias[i] = (const float*)d_in[2 + 3 * i];
    knn[i]  = (const int*)d_in[3 + 3 * i];
  }
  const float* fc_w = (const float*)d_in[16];
  const float* fc_b = (const float*)d_in[17];
  float* out = (float*)d_out;

  static const int DIMS[5] = {7200, 3600, 1800, 900, 450};

  // Workspace (floats), 125.3 MB, all slice-major [t][8][d][16]:
  //   A  : 16*8*7200*16 = 14,745,600   (mem0 -> mem2 -> mem4)
  //   XB : 8*8*14400*16 = 14,745,600   (xT half-slab; later mem1 + mem3)
  //   S  : 2*8*7200*16  =  1,843,200   (layer-0 syn/mem carry)
  float* A  = (float*)d_ws;
  float* XB = A + 14745600;
  float* S  = XB + 14745600;

  float* mem0 = A;
  float* mem1 = XB;
  float* mem2 = A;
  float* mem3 = XB + 7372800;
  float* mem4 = A;

  // ---- Layer 0 in two 8-t stages (xT half-slab reuse) ----
  for (int stage = 0; stage < 2; ++stage) {
    const int t0 = stage * 8;
    transpose_x4_kernel<<<dim3(IN_DIM / 64, B / 64, 8), 256, 0, stream>>>(
        x, XB, t0);
    launch_layer(XB, w[0], bias[0], knn[0],
                 mem0 + (size_t)t0 * NSL * DIMS[0] * SW, S, DIMS[0], IN_DIM,
                 8, /*load=*/stage, /*save=*/stage == 0, stream);
  }

  // ---- Layers 1..4, all 16 timesteps ----
  const float* src = mem0;
  float* dsts[4] = {mem1, mem2, mem3, mem4};
  for (int i = 1; i < 5; ++i) {
    launch_layer(src, w[i], bias[i], knn[i], dsts[i - 1], nullptr, DIMS[i],
                 DIMS[i - 1], 16, 0, 0, stream);
    src = dsts[i - 1];
  }

  fc_kernel<<<1, 128, 0, stream>>>(mem4 + (size_t)15 * NSL * DIMS[4] * SW,
                                   fc_w, fc_b, out);
}

// Round 7
// 400.261 us; speedup vs baseline: 2.3665x; 1.0195x over previous
//
#include <hip/hip_runtime.h>

#define ALPHA 0.9f
#define BETA  0.8f
#define K     25
#define B     128
#define T     16
#define IN_DIM 14400
#define NSL   8      // batch slices (= XCDs)
#define SW    16     // slice width (batch elems)
#define NPG   32     // neurons per group (128 thr = 32 n x 4 quads)

// ---------------------------------------------------------------------------
// Transpose one 8-t slab of x (B,T,IN) -> xTh[8t][8e][IN][16] (slice-major:
// every 64B line belongs to exactly one XCD's slice).
// ---------------------------------------------------------------------------
__global__ __launch_bounds__(256) void transpose_x4_kernel(
    const float* __restrict__ x, float* __restrict__ xTh, int t0) {
  __shared__ float tile[64][65];
  const int tl = blockIdx.z;            // local t 0..7
  const int t  = t0 + tl;
  const int i0 = blockIdx.x * 64;       // feature tile
  const int b0 = blockIdx.y * 64;       // batch tile
  const int tid = threadIdx.x;

  const int fi = (tid & 15) * 4;        // feature quad
  const int bi = tid >> 4;              // batch row 0..15
#pragma unroll
  for (int p = 0; p < 4; ++p) {
    const int b = bi + p * 16;
    const float4 v = *(const float4*)&x[(size_t)(b0 + b) * (T * IN_DIM) +
                                        (size_t)t * IN_DIM + i0 + fi];
    tile[fi + 0][b] = v.x;
    tile[fi + 1][b] = v.y;
    tile[fi + 2][b] = v.z;
    tile[fi + 3][b] = v.w;
  }
  __syncthreads();
  const int bq = (tid & 15) * 4;        // batch quad (0,4,..,60)
  const int fr = tid >> 4;              // feature row 0..15
  const int e  = (b0 + bq) >> 4;        // slice
  const int bl = bq & 15;               // 0,4,8,12
#pragma unroll
  for (int p = 0; p < 4; ++p) {
    const int f = fr + p * 16;
    float4 v;
    v.x = tile[f][bq + 0];
    v.y = tile[f][bq + 1];
    v.z = tile[f][bq + 2];
    v.w = tile[f][bq + 3];
    *(float4*)&xTh[(((size_t)tl * NSL + e) * IN_DIM + (i0 + f)) * SW + bl] = v;
  }
}

// ---------------------------------------------------------------------------
// LCN+LIF layer: ONE neuron-group per block, t-inner (idx/w hoisted to regs,
// read exactly once). hsrc: [nt][8][dprev][16], memout: [nt][8][dim][16],
// state: [2][8][dim][16]. Thread = (neuron, batch-quad): float4 gathers,
// 4 independent FMA lanes x 2 partials. blockIdx%8 = slice = XCD (grid is
// always <= residency at 128thr/block => launch round-robin mapping exact).
// For L1..L4 the whole per-XCD src trace (<=3.7MB) is L2-resident; for L0
// the uniform short 8-t sweeps keep cross-block drift within L2 (proven
// round 3: FETCH was exact at 60.5MB with this structure).
// ---------------------------------------------------------------------------
template <int NT>
__global__ __launch_bounds__(128, 4) void lcn_layer_q(
    const float* __restrict__ hsrc, const float* __restrict__ w,
    const float* __restrict__ bias, const int* __restrict__ knn,
    float* __restrict__ memout, float* __restrict__ state,
    int dim, int dprev, int load_state, int save_state) {
  const int e  = blockIdx.x & 7;          // slice -> XCD
  const int g  = blockIdx.x >> 3;         // neuron group
  const int nl = threadIdx.x >> 2;        // neuron in group (0..31)
  const int q  = threadIdx.x & 3;         // batch quad (0..3)
  const int d  = g * NPG + nl;
  const bool act = d < dim;
  const int dc = act ? d : dim - 1;       // clamped for loads
  const int bl = q * 4;

  int   idx[K];
  float wr[K];
#pragma unroll
  for (int k = 0; k < K; ++k) {
    idx[k] = knn[dc * K + k] * SW + bl;   // within-slice element offset
    wr[k]  = w[dc * K + k];
  }
  const float bi = bias[dc];

  float4 s = make_float4(0.f, 0.f, 0.f, 0.f);
  float4 m = make_float4(0.f, 0.f, 0.f, 0.f);
  if (load_state) {
    const size_t so = ((size_t)e * dim + dc) * SW + bl;
    s = *(const float4*)&state[so];
    m = *(const float4*)&state[(size_t)NSL * dim * SW + so];
  }

  const size_t sliceA = (size_t)dprev * SW;  // per-(t,e) src stride
  const float* hp0 = hsrc + (size_t)e * sliceA;

  for (int t = 0; t < NT; ++t) {
    const float* hp = hp0 + (size_t)t * NSL * sliceA;
    // two partial accumulators per component -> chain depth ~13
    float4 a0 = make_float4(bi, 0.f, bi, 0.f);
    float4 a1 = make_float4(0.f, bi, 0.f, bi);
    float4 acc0 = make_float4(0, 0, 0, 0), acc1 = make_float4(0, 0, 0, 0);
#pragma unroll
    for (int k = 0; k < K; k += 2) {
      const float4 h0 = *(const float4*)&hp[idx[k]];
      acc0.x = fmaf(wr[k], h0.x, acc0.x);
      acc0.y = fmaf(wr[k], h0.y, acc0.y);
      acc0.z = fmaf(wr[k], h0.z, acc0.z);
      acc0.w = fmaf(wr[k], h0.w, acc0.w);
      if (k + 1 < K) {
        const float4 h1 = *(const float4*)&hp[idx[k + 1]];
        acc1.x = fmaf(wr[k + 1], h1.x, acc1.x);
        acc1.y = fmaf(wr[k + 1], h1.y, acc1.y);
        acc1.z = fmaf(wr[k + 1], h1.z, acc1.z);
        acc1.w = fmaf(wr[k + 1], h1.w, acc1.w);
      }
    }
    (void)a0; (void)a1;
    const float4 acc = make_float4(acc0.x + acc1.x + bi, acc0.y + acc1.y + bi,
                                   acc0.z + acc1.z + bi, acc0.w + acc1.w + bi);
    s.x = ALPHA * s.x + acc.x;
    s.y = ALPHA * s.y + acc.y;
    s.z = ALPHA * s.z + acc.z;
    s.w = ALPHA * s.w + acc.w;
    float4 r;
    r.x = (m.x > 1.0f) ? 1.0f : 0.0f;  // reset from PREVIOUS membrane
    r.y = (m.y > 1.0f) ? 1.0f : 0.0f;
    r.z = (m.z > 1.0f) ? 1.0f : 0.0f;
    r.w = (m.w > 1.0f) ? 1.0f : 0.0f;
    m.x = BETA * m.x + s.x - r.x;
    m.y = BETA * m.y + s.y - r.y;
    m.z = BETA * m.z + s.z - r.z;
    m.w = BETA * m.w + s.w - r.w;
    if (act) {
      *(float4*)&memout[(((size_t)t * NSL + e) * dim + d) * SW + bl] = m;
    }
  }

  if (save_state && act) {
    const size_t so = ((size_t)e * dim + d) * SW + bl;
    *(float4*)&state[so] = s;
    *(float4*)&state[(size_t)NSL * dim * SW + so] = m;
  }
}

// Final FC on last timestep's layer-4 membrane: mem4_t15 [8][450][16].
__global__ __launch_bounds__(128) void fc_kernel(
    const float* __restrict__ mem4_t15, const float* __restrict__ fc_w,
    const float* __restrict__ fc_b, float* __restrict__ out) {
  const int b  = threadIdx.x;
  const int e  = b >> 4;
  const int bl = b & 15;
  float a0 = fc_b[0], a1 = fc_b[1];
  for (int d = 0; d < 450; ++d) {
    const float h = mem4_t15[((size_t)e * 450 + d) * SW + bl];
    a0 += fc_w[d] * h;
    a1 += fc_w[450 + d] * h;
  }
  out[b * 2 + 0] = a0;
  out[b * 2 + 1] = a1;
}

extern "C" void kernel_launch(void* const* d_in, const int* in_sizes, int n_in,
                              void* d_out, int out_size, void* d_ws,
                              size_t ws_size, hipStream_t stream) {
  (void)in_sizes; (void)n_in; (void)out_size; (void)ws_size;
  const float* x = (const float*)d_in[0];
  const float* w[5];
  const float* bias[5];
  const int* knn[5];
  for (int i = 0; i < 5; ++i) {
    w[i]    = (const float*)d_in[1 + 3 * i];
    bias[i] = (const float*)d_in[2 + 3 * i];
    knn[i]  = (const int*)d_in[3 + 3 * i];
  }
  const float* fc_w = (const float*)d_in[16];
  const float* fc_b = (const float*)d_in[17];
  float* out = (float*)d_out;

  static const int DIMS[5] = {7200, 3600, 1800, 900, 450};

  // Workspace (floats), 125.3 MB, all slice-major [t][8][d][16]:
  //   A  : 16*8*7200*16 = 14,745,600   (mem0 -> mem2 -> mem4)
  //   XB : 8*8*14400*16 = 14,745,600   (xT half-slab; later mem1 + mem3)
  //   S  : 2*8*7200*16  =  1,843,200   (layer-0 syn/mem carry)
  float* A  = (float*)d_ws;
  float* XB = A + 14745600;
  float* S  = XB + 14745600;

  float* mem0 = A;
  float* mem1 = XB;
  float* mem2 = A;
  float* mem3 = XB + 7372800;
  float* mem4 = A;

  // ---- Layer 0 in two 8-t stages (xT half-slab reuse) ----
  for (int stage = 0; stage < 2; ++stage) {
    const int t0 = stage * 8;
    transpose_x4_kernel<<<dim3(IN_DIM / 64, B / 64, 8), 256, 0, stream>>>(
        x, XB, t0);
    const int ng = (DIMS[0] + NPG - 1) / NPG;  // 225
    lcn_layer_q<8><<<ng * NSL, 128, 0, stream>>>(
        XB, w[0], bias[0], knn[0], mem0 + (size_t)t0 * NSL * DIMS[0] * SW, S,
        DIMS[0], IN_DIM, /*load=*/stage, /*save=*/stage == 0);
  }

  // ---- Layers 1..4, all 16 timesteps ----
  const float* src = mem0;
  float* dsts[4] = {mem1, mem2, mem3, mem4};
  for (int i = 1; i < 5; ++i) {
    const int ng = (DIMS[i] + NPG - 1) / NPG;
    lcn_layer_q<16><<<ng * NSL, 128, 0, stream>>>(
        src, w[i], bias[i], knn[i], dsts[i - 1], nullptr, DIMS[i],
        DIMS[i - 1], 0, 0);
    src = dsts[i - 1];
  }

  fc_kernel<<<1, 128, 0, stream>>>(mem4 + (size_t)15 * NSL * DIMS[4] * SW,
                                   fc_w, fc_b, out);
}